// Round 5
// baseline (246.714 us; speedup 1.0000x reference)
//
#include <hip/hip_runtime.h>
#include <math.h>

// Problem constants (from reference): N=65536 rows, D=512 features, K=5 centroids.
#define LFR_N 65536
#define LFR_D 512
#define LFR_K 5
#define ROWS    4                           // rows per wave per iteration
#define BLOCKS  2048                        // 8 blocks/CU
#define NWAVES  (BLOCKS * 4)                // 8192 waves
#define ITERS   (LFR_N / (NWAVES * ROWS))   // 2 iterations/wave

// R5: SPLIT READ AND WRITE STREAMS.
// R0-R4 post-mortem: four structurally different kernels (VALU -50%, shuffle
// -60%, prefetch streaming, canonical 1KB-span coalescing) ALL land at 82-88us
// with HBM pinned at 2.3-2.5 TB/s and every CU-side pipe <35% busy. True data
// motion is 134MB read + 134MB write = 268MB -> 43us at the 6.3TB/s roofline;
// we are at exactly 2x. The one thing never varied: read and write streams
// interleaved at 2KB grain in one kernel. Reference point: the harness's
// fillBufferAligned (pure write) hits 6.7 TB/s on this same buffer.
// Hypothesis: mixed-stream read/write turnaround is the cap -> unmix.
//   Kernel A: x -> dist -> softmax -> map+pred   (134MB read,  1.6MB write)
//   Kernel B: map x centroids -> rec             (1.3MB read, 134MB write)
// Bitwise-identical results (B consumes the exact f32 map A stored).
// This is also the decisive ablation: per-dispatch counters next round show
// which stream carries the pathology.

// ---------------------------------------------------------------- kernel A --
__global__ __launch_bounds__(256) void lfr_map_kernel(
    const float* __restrict__ x,        // (N, D)
    const float* __restrict__ alpha,    // (D,)
    const float* __restrict__ w,        // (K, 1)
    const float* __restrict__ cent,     // (K, D)
    float* __restrict__ out_map,        // (N, K)
    float* __restrict__ out_pred)       // (N,)
{
    const int lane = threadIdx.x & 63;
    const int wib  = threadIdx.x >> 6;
    const int wid  = blockIdx.x * (blockDim.x >> 6) + wib;

    const int dA  = lane * 4;        // lane's float4 at d=dA and d=dA+256
    const int hi  = (lane >> 5) & 1; // row bit1 for reduce-scatter
    const int mid = (lane >> 4) & 1; // row bit0

    // ---- per-lane constants (loaded once per wave) ----
    float al[8];
    {
        float4 a0 = *(const float4*)(alpha + dA);
        float4 a1 = *(const float4*)(alpha + dA + 256);
        al[0]=a0.x; al[1]=a0.y; al[2]=a0.z; al[3]=a0.w;
        al[4]=a1.x; al[5]=a1.y; al[6]=a1.z; al[7]=a1.w;
    }
    float c[LFR_K][8];
    #pragma unroll
    for (int k = 0; k < LFR_K; ++k) {
        float4 c0 = *(const float4*)(cent + k * LFR_D + dA);
        float4 c1 = *(const float4*)(cent + k * LFR_D + dA + 256);
        c[k][0]=c0.x; c[k][1]=c0.y; c[k][2]=c0.z; c[k][3]=c0.w;
        c[k][4]=c1.x; c[k][5]=c1.y; c[k][6]=c1.z; c[k][7]=c1.w;
    }
    float m2a[8];                       // -2*alpha
    #pragma unroll
    for (int j = 0; j < 8; ++j) m2a[j] = -2.0f * al[j];
    float cst[LFR_K];                   // lane-partial of sum_d alpha*c_k^2
    #pragma unroll
    for (int k = 0; k < LFR_K; ++k) {
        float s = 0.0f;
        #pragma unroll
        for (int j = 0; j < 8; ++j) {
            float u = al[j] * c[k][j];
            s = fmaf(u, c[k][j], s);
        }
        cst[k] = s;
    }
    float sigw[LFR_K];
    #pragma unroll
    for (int k = 0; k < LFR_K; ++k)
        sigw[k] = 1.0f / (1.0f + __expf(-w[k]));

    const size_t XSTEP = (size_t)NWAVES * ROWS * LFR_D;
    const float* xp = x + (size_t)wid * ROWS * LFR_D;

    // prologue: block 0 loads in flight
    float4 xl[ROWS][2];
    #pragma unroll
    for (int r = 0; r < ROWS; ++r) {
        xl[r][0] = *(const float4*)(xp + (size_t)r * LFR_D + dA);
        xl[r][1] = *(const float4*)(xp + (size_t)r * LFR_D + dA + 256);
    }

    for (int it = 0; it < ITERS; ++it) {
        const size_t rbase = (size_t)(it * NWAVES + wid) * ROWS;

        float p[ROWS][LFR_K];
        #pragma unroll
        for (int r = 0; r < ROWS; ++r) {
            float v[8];
            v[0]=m2a[0]*xl[r][0].x; v[1]=m2a[1]*xl[r][0].y;
            v[2]=m2a[2]*xl[r][0].z; v[3]=m2a[3]*xl[r][0].w;
            v[4]=m2a[4]*xl[r][1].x; v[5]=m2a[5]*xl[r][1].y;
            v[6]=m2a[6]*xl[r][1].z; v[7]=m2a[7]*xl[r][1].w;
            #pragma unroll
            for (int k = 0; k < LFR_K; ++k) {
                float acc = cst[k];
                #pragma unroll
                for (int j = 0; j < 8; ++j) acc = fmaf(c[k][j], v[j], acc);
                p[r][k] = acc;
            }
            if (it + 1 < ITERS) {       // prefetch next block's row r
                const float* nx = xp + XSTEP + (size_t)r * LFR_D;
                xl[r][0] = *(const float4*)(nx + dA);
                xl[r][1] = *(const float4*)(nx + dA + 256);
            }
        }

        // reduce-scatter: rows -> 16-lane groups (group g owns row rbase+g)
        float q[2][LFR_K];
        #pragma unroll
        for (int r2 = 0; r2 < 2; ++r2) {
            #pragma unroll
            for (int k = 0; k < LFR_K; ++k) {
                float send = hi ? p[r2][k]     : p[2 + r2][k];
                float keep = hi ? p[2 + r2][k] : p[r2][k];
                q[r2][k] = keep + __shfl_xor(send, 32);
            }
        }
        float s[LFR_K];
        #pragma unroll
        for (int k = 0; k < LFR_K; ++k) {
            float send = mid ? q[0][k] : q[1][k];
            float keep = mid ? q[1][k] : q[0][k];
            s[k] = keep + __shfl_xor(send, 16);
        }
        #pragma unroll
        for (int off = 8; off > 0; off >>= 1) {
            #pragma unroll
            for (int k = 0; k < LFR_K; ++k)
                s[k] += __shfl_xor(s[k], off);
        }

        // softmax over K (row g = lane>>4), write map+pred from sublane 0
        float e[LFR_K];
        {
            float mx = s[0];
            #pragma unroll
            for (int k = 1; k < LFR_K; ++k) mx = fmaxf(mx, s[k]);
            float sum = 0.0f;
            #pragma unroll
            for (int k = 0; k < LFR_K; ++k) { e[k] = __expf(s[k] - mx); sum += e[k]; }
            float inv = 1.0f / sum;
            #pragma unroll
            for (int k = 0; k < LFR_K; ++k) e[k] *= inv;
        }
        if ((lane & 15) == 0) {
            const int g = lane >> 4;
            float* mp = out_map + (rbase + g) * LFR_K;
            *(float4*)(mp) = make_float4(e[0], e[1], e[2], e[3]);
            mp[4] = e[4];
            float pr = e[0] * sigw[0];
            #pragma unroll
            for (int k = 1; k < LFR_K; ++k) pr = fmaf(e[k], sigw[k], pr);
            out_pred[rbase + g] = pr;
        }

        xp += XSTEP;
    }
}

// ---------------------------------------------------------------- kernel B --
// Pure write stream: rec[n,:] = sum_k map[n,k] * cent[k,:].
// Reads: map 1.3MB (L2/L3-hit) + cent 10KB. Writes: 134MB coalesced.
__global__ __launch_bounds__(256) void lfr_rec_kernel(
    const float* __restrict__ cent,     // (K, D)
    const float* __restrict__ map,      // (N, K) -- written by kernel A
    float* __restrict__ out_rec)        // (N, D)
{
    const int lane = threadIdx.x & 63;
    const int wib  = threadIdx.x >> 6;
    const int wid  = blockIdx.x * (blockDim.x >> 6) + wib;
    const int dA   = lane * 4;

    float c[LFR_K][8];
    #pragma unroll
    for (int k = 0; k < LFR_K; ++k) {
        float4 c0 = *(const float4*)(cent + k * LFR_D + dA);
        float4 c1 = *(const float4*)(cent + k * LFR_D + dA + 256);
        c[k][0]=c0.x; c[k][1]=c0.y; c[k][2]=c0.z; c[k][3]=c0.w;
        c[k][4]=c1.x; c[k][5]=c1.y; c[k][6]=c1.z; c[k][7]=c1.w;
    }

    for (int it = 0; it < ITERS; ++it) {
        const size_t rbase = (size_t)(it * NWAVES + wid) * ROWS;

        // wave-uniform broadcast loads of the 4 rows' mapping (20 contiguous
        // floats; same address across lanes -> single-line hit, L2-resident)
        const float* mp = map + rbase * LFR_K;
        float M[ROWS][LFR_K];
        #pragma unroll
        for (int r = 0; r < ROWS; ++r)
            #pragma unroll
            for (int k = 0; k < LFR_K; ++k)
                M[r][k] = mp[r * LFR_K + k];

        #pragma unroll
        for (int r = 0; r < ROWS; ++r) {
            float rv[8];
            #pragma unroll
            for (int j = 0; j < 8; ++j) {
                float acc = M[r][0] * c[0][j];
                #pragma unroll
                for (int k = 1; k < LFR_K; ++k) acc = fmaf(M[r][k], c[k][j], acc);
                rv[j] = acc;
            }
            float* rr = out_rec + (rbase + r) * LFR_D;
            *(float4*)(rr + dA)       = make_float4(rv[0], rv[1], rv[2], rv[3]);
            *(float4*)(rr + dA + 256) = make_float4(rv[4], rv[5], rv[6], rv[7]);
        }
    }
}

extern "C" void kernel_launch(void* const* d_in, const int* in_sizes, int n_in,
                              void* d_out, int out_size, void* d_ws, size_t ws_size,
                              hipStream_t stream) {
    const float* x     = (const float*)d_in[0];   // (N, D)
    // d_in[1] = is_protected — unused by the reference computation
    const float* alpha = (const float*)d_in[2];   // (D,)
    const float* w     = (const float*)d_in[3];   // (K, 1)
    const float* cent  = (const float*)d_in[4];   // (K, D)

    float* out   = (float*)d_out;
    float* o_map = out;                                         // N*K
    float* o_rec = out + (size_t)LFR_N * LFR_K;                 // N*D
    float* o_prd = out + (size_t)LFR_N * LFR_K + (size_t)LFR_N * LFR_D;  // N

    dim3 grid(BLOCKS), block(256);
    // A: read-stream pass (x -> map, pred). B: write-stream pass (map -> rec).
    // Same-stream ordering makes B see A's map.
    lfr_map_kernel<<<grid, block, 0, stream>>>(x, alpha, w, cent, o_map, o_prd);
    lfr_rec_kernel<<<grid, block, 0, stream>>>(cent, o_map, o_rec);
}